// Round 3
// baseline (62.216 us; speedup 1.0000x reference)
//
#include <hip/hip_runtime.h>
#include <math.h>

#define EPS_COS 1e-8f
#define EPS_ADD 1e-12f

typedef float f4 __attribute__((ext_vector_type(4)));

// ---------------------------------------------------------------------------
// Kernel 1: scores. grid = B * (N/256) blocks, 256 threads each.
// Each block computes t[b, row] = beta*cos_sim(mem[b,row,:], kappa[b,:]) for a
// 256-row chunk. Mapping: 16 lanes per row (lane l16 holds float4 #l16 of the
// row); each wave instruction covers 4 rows x 256B contiguous. 4-deep register
// double buffer; nontemporal loads (memory is read exactly once).
// Scores are written to d_out (B*N floats); kernel 2 overwrites it.
// ---------------------------------------------------------------------------
__global__ __launch_bounds__(256) void ntm_scores_kernel(
    const float* __restrict__ beta,    // [B,1]
    const float* __restrict__ kappa,   // [B,64]
    const float* __restrict__ mem,     // [B,N,64]
    float* __restrict__ t_out,         // [B,N]
    int N, int chunks)
{
    const int blk  = blockIdx.x;
    const int b    = blk / chunks;
    const int c    = blk % chunks;
    const int tid  = threadIdx.x;
    const int lane = tid & 63;
    const int wave = tid >> 6;
    const int l16  = lane & 15;
    const int rg   = lane >> 4;          // row within the wave's 4-row group
    const int r_off = wave * 4 + rg;     // 0..15: row offset within a round

    // kappa fragment + norm
    f4 kv = *reinterpret_cast<const f4*>(kappa + (size_t)b * 64 + l16 * 4);
    kv += (f4)EPS_ADD;
    float nb2 = kv.x * kv.x + kv.y * kv.y + kv.z * kv.z + kv.w * kv.w;
#pragma unroll
    for (int m = 1; m < 16; m <<= 1) nb2 += __shfl_xor(nb2, m);
    const float bscale = beta[b] / fmaxf(sqrtf(nb2), EPS_COS);

    const int row_base = c * 256;
    const f4* p = reinterpret_cast<const f4*>(mem) +
                  ((size_t)b * N + row_base + r_off) * 16 + l16;
    // one round = 16 rows = 256 f4 stride
    f4 a[4];
#pragma unroll
    for (int u = 0; u < 4; ++u) a[u] = __builtin_nontemporal_load(p + u * 256);

    const size_t obase = (size_t)b * N + row_base + r_off;

    for (int r0 = 0; r0 < 16; r0 += 4) {
        f4 cb[4];
#pragma unroll
        for (int u = 0; u < 4; ++u) cb[u] = a[u];
        if (r0 + 4 < 16) {
#pragma unroll
            for (int u = 0; u < 4; ++u)
                a[u] = __builtin_nontemporal_load(p + (size_t)(r0 + 4 + u) * 256);
        }
#pragma unroll
        for (int u = 0; u < 4; ++u) {
            const f4 v = cb[u];
            float d  = v.x * kv.x + v.y * kv.y + v.z * kv.z + v.w * kv.w;
            float n2 = v.x * v.x + v.y * v.y + v.z * v.z + v.w * v.w;
#pragma unroll
            for (int m = 1; m < 16; m <<= 1) {
                d  += __shfl_xor(d, m);
                n2 += __shfl_xor(n2, m);
            }
            const float t = bscale * d * rsqrtf(fmaxf(n2, 1e-16f));
            if (l16 == 0) t_out[obase + (r0 + u) * 16] = t;
        }
    }
}

// ---------------------------------------------------------------------------
// Kernel 2: softmax + interpolate + shift + sharpen + normalize.
// grid = B blocks x 1024 threads. Reads t from d_out, overwrites d_out.
// ---------------------------------------------------------------------------
constexpr int NT2    = 1024;
constexpr int NW2    = NT2 / 64;   // 16
constexpr int MAX_N  = 4096;

__global__ __launch_bounds__(NT2, 1) void ntm_tail_kernel(
    const float* __restrict__ gamma,   // [B,1]
    const float* __restrict__ g,       // [B,1]
    const float* __restrict__ s,       // [B,S]
    const float* __restrict__ w_prev,  // [B,N]
    float* __restrict__ out,           // [B,N] (holds t on entry)
    int N, int S)
{
    const int b    = blockIdx.x;
    const int tid  = threadIdx.x;
    const int lane = tid & 63;
    const int wave = tid >> 6;

    __shared__ float t_sh[MAX_N];
    __shared__ float w_sh[MAX_N];
    __shared__ float red[NW2];

    float* tb = out + (size_t)b * N;

    // ---- load scores + max ----
    float tmax = -INFINITY;
    for (int i = tid; i < N; i += NT2) {
        const float v = tb[i];
        t_sh[i] = v;
        tmax = fmaxf(tmax, v);
    }
#pragma unroll
    for (int m = 1; m < 64; m <<= 1) tmax = fmaxf(tmax, __shfl_xor(tmax, m));
    if (lane == 0) red[wave] = tmax;
    __syncthreads();
    float gmax = red[0];
#pragma unroll
    for (int i = 1; i < NW2; ++i) gmax = fmaxf(gmax, red[i]);
    __syncthreads();

    // ---- exp + sum ----
    float lsum = 0.0f;
    for (int i = tid; i < N; i += NT2) {
        const float e = expf(t_sh[i] - gmax);
        t_sh[i] = e;
        lsum += e;
    }
#pragma unroll
    for (int m = 1; m < 64; m <<= 1) lsum += __shfl_xor(lsum, m);
    if (lane == 0) red[wave] = lsum;
    __syncthreads();
    float tot = 0.0f;
#pragma unroll
    for (int i = 0; i < NW2; ++i) tot += red[i];
    __syncthreads();

    // ---- interpolate ----
    const float gv = g[b];
    const float inv_tot = 1.0f / tot;
    for (int i = tid; i < N; i += NT2) {
        const float wc = t_sh[i] * inv_tot;
        w_sh[i] = gv * wc + (1.0f - gv) * w_prev[(size_t)b * N + i];
    }
    __syncthreads();

    // ---- circular shift + sharpen ----
    const float gam = gamma[b];
    float sv[8];
    const int Sc = (S < 8) ? S : 8;
    for (int j = 0; j < Sc; ++j) sv[j] = s[(size_t)b * S + j];

    float ssum = 0.0f;
    for (int i = tid; i < N; i += NT2) {
        float wh = 0.0f;
        for (int j = 0; j < Sc; ++j) {
            int idx = i + j - 1 + N;
            if (idx >= N) idx -= N;
            if (idx >= N) idx -= N;
            wh += sv[j] * w_sh[idx];
        }
        const float sh = powf(wh, gam);
        t_sh[i] = sh;
        ssum += sh;
    }
#pragma unroll
    for (int m = 1; m < 64; m <<= 1) ssum += __shfl_xor(ssum, m);
    if (lane == 0) red[wave] = ssum;
    __syncthreads();
    float stot = 0.0f;
#pragma unroll
    for (int i = 0; i < NW2; ++i) stot += red[i];

    // ---- normalize + write ----
    const float inv_den = 1.0f / (stot + EPS_ADD);
    for (int i = tid; i < N; i += NT2) {
        tb[i] = t_sh[i] * inv_den;
    }
}

extern "C" void kernel_launch(void* const* d_in, const int* in_sizes, int n_in,
                              void* d_out, int out_size, void* d_ws, size_t ws_size,
                              hipStream_t stream) {
    const float* beta   = (const float*)d_in[0];
    const float* kappa  = (const float*)d_in[1];
    const float* gamma  = (const float*)d_in[2];
    const float* g      = (const float*)d_in[3];
    const float* s      = (const float*)d_in[4];
    const float* w_prev = (const float*)d_in[5];
    const float* mem    = (const float*)d_in[6];
    float* out          = (float*)d_out;

    const int B = in_sizes[0];            // beta is (B,1)
    const int N = in_sizes[5] / B;        // w_prev is (B,N)
    const int S = in_sizes[4] / B;        // s is (B,S)
    const int chunks = N / 256;           // N % 256 == 0 (N = 4096)

    ntm_scores_kernel<<<B * chunks, 256, 0, stream>>>(
        beta, kappa, mem, out, N, chunks);
    ntm_tail_kernel<<<B, NT2, 0, stream>>>(
        gamma, g, s, w_prev, out, N, S);
}

// Round 4
// 54.234 us; speedup vs baseline: 1.1472x; 1.1472x over previous
//
#include <hip/hip_runtime.h>
#include <math.h>

#define EPS_COS 1e-8f
#define EPS_ADD 1e-12f

typedef float f4 __attribute__((ext_vector_type(4)));

// One block per batch (grid = B = 256 = #CUs), 1024 threads = 16 waves.
// Streaming pass: 16 lanes per row (lane l16 holds float4 #l16 of the 64-elem
// row). One wave load instruction = 4 rows x 256B contiguous = 1 KiB. 4-deep
// register prefetch. Scores |t| < 1 (beta in [0,1), cos in [-1,1]) so softmax
// needs no max subtraction: exp + denominator are computed inline with the
// stream. Tail: 1 reduce + in-place interpolate + shift/powf in registers +
// 1 reduce + vector store. Assumes N == 4096 (= 1024 threads * 4), M == 64.

constexpr int NTHREADS = 1024;
constexpr int NWAVES   = NTHREADS / 64;   // 16
constexpr int MAX_N    = 4096;

__global__ __launch_bounds__(NTHREADS, 1) void ntm_fused_kernel(
    const float* __restrict__ beta,    // [B,1]
    const float* __restrict__ kappa,   // [B,64]
    const float* __restrict__ gamma,   // [B,1]
    const float* __restrict__ g,       // [B,1]
    const float* __restrict__ s,       // [B,S]
    const float* __restrict__ w_prev,  // [B,N]
    const float* __restrict__ mem,     // [B,N,64]
    float* __restrict__ out,           // [B,N]
    int N, int S)
{
    const int b    = blockIdx.x;
    const int tid  = threadIdx.x;
    const int lane = tid & 63;
    const int wave = tid >> 6;
    const int l16  = lane & 15;
    const int rg   = lane >> 4;          // row within the wave's 4-row group

    __shared__ float sh[MAX_N];          // e values -> interpolated weights
    __shared__ float red[NWAVES];

    // ---- prefetch w_prev into registers (overlaps the whole stream) ----
    const f4 wp_reg = reinterpret_cast<const f4*>(w_prev + (size_t)b * N)[tid];

    // ---- kappa fragment + norm ----
    f4 kv = reinterpret_cast<const f4*>(kappa + (size_t)b * 64)[l16];
    kv += (f4)EPS_ADD;
    float nb2 = kv.x * kv.x + kv.y * kv.y + kv.z * kv.z + kv.w * kv.w;
#pragma unroll
    for (int m = 1; m < 16; m <<= 1) nb2 += __shfl_xor(nb2, m);
    const float bscale = beta[b] / fmaxf(sqrtf(nb2), EPS_COS);

    // ---- streaming pass: 64 rows/round (16 waves x 4 rows), 4-deep prefetch ----
    const int nRound = N >> 6;           // 64 for N=4096
    const int row0   = wave * 4 + rg;
    const f4* p = reinterpret_cast<const f4*>(mem + (size_t)b * N * 64)
                  + (size_t)row0 * 16 + l16;
    // round stride = 64 rows * 16 f4 = 1024 f4

    f4 a0 = p[0], a1 = p[1024], a2 = p[2048], a3 = p[3072];
    float lsum = 0.0f;

    for (int it = 0; it < nRound; it += 4) {
        const f4 c0 = a0, c1 = a1, c2 = a2, c3 = a3;
        if (it + 4 < nRound) {
            const f4* pn = p + (size_t)(it + 4) * 1024;
            a0 = pn[0]; a1 = pn[1024]; a2 = pn[2048]; a3 = pn[3072];
        }
#pragma unroll
        for (int u = 0; u < 4; ++u) {
            const f4 v = (u == 0) ? c0 : (u == 1) ? c1 : (u == 2) ? c2 : c3;
            float d  = v.x * kv.x + v.y * kv.y + v.z * kv.z + v.w * kv.w;
            float n2 = v.x * v.x + v.y * v.y + v.z * v.z + v.w * v.w;
#pragma unroll
            for (int m = 1; m < 16; m <<= 1) {
                d  += __shfl_xor(d, m);
                n2 += __shfl_xor(n2, m);
            }
            const float t = bscale * d * rsqrtf(fmaxf(n2, 1e-16f));
            const float e = expf(t);                 // |t| < 1: no max needed
            if (l16 == 0) {
                sh[row0 + (it + u) * 64] = e;
                lsum += e;
            }
        }
    }

    // ---- block reduce: softmax denominator ----
#pragma unroll
    for (int m = 1; m < 64; m <<= 1) lsum += __shfl_xor(lsum, m);
    if (lane == 0) red[wave] = lsum;
    __syncthreads();                      // also covers all sh[] writes
    float tot = 0.0f;
#pragma unroll
    for (int i = 0; i < NWAVES; ++i) tot += red[i];

    // ---- interpolate in place (one f4 per thread) ----
    const float gv = g[b];
    const float ws = gv / tot;            // g * (e / tot)
    f4* sh4 = reinterpret_cast<f4*>(sh);
    {
        const f4 ev = sh4[tid];
        sh4[tid] = ws * ev + (1.0f - gv) * wp_reg;
    }
    __syncthreads();

    // ---- circular shift + sharpen (results stay in registers) ----
    const float gam = gamma[b];
    float sv[8];
    const int Sc = (S < 8) ? S : 8;
    for (int j = 0; j < Sc; ++j) sv[j] = s[(size_t)b * S + j];

    const int i0 = tid * 4;
    const int mask = N - 1;               // N is a power of two
    float o[4];
    float ssum = 0.0f;
#pragma unroll
    for (int k = 0; k < 4; ++k) {
        float wh = 0.0f;
        for (int j = 0; j < Sc; ++j) {
            const int idx = (i0 + k + j - 1) & mask;
            wh += sv[j] * sh[idx];
        }
        o[k] = powf(wh, gam);
        ssum += o[k];
    }

    // ---- block reduce: sharpen denominator ----
#pragma unroll
    for (int m = 1; m < 64; m <<= 1) ssum += __shfl_xor(ssum, m);
    if (lane == 0) red[wave] = ssum;      // safe: red reads (tot) were pre-barrier
    __syncthreads();
    float stot = 0.0f;
#pragma unroll
    for (int i = 0; i < NWAVES; ++i) stot += red[i];

    // ---- normalize + vector store ----
    const float inv_den = 1.0f / (stot + EPS_ADD);
    f4 ov;
    ov.x = o[0] * inv_den; ov.y = o[1] * inv_den;
    ov.z = o[2] * inv_den; ov.w = o[3] * inv_den;
    reinterpret_cast<f4*>(out + (size_t)b * N)[tid] = ov;
}

extern "C" void kernel_launch(void* const* d_in, const int* in_sizes, int n_in,
                              void* d_out, int out_size, void* d_ws, size_t ws_size,
                              hipStream_t stream) {
    const float* beta   = (const float*)d_in[0];
    const float* kappa  = (const float*)d_in[1];
    const float* gamma  = (const float*)d_in[2];
    const float* g      = (const float*)d_in[3];
    const float* s      = (const float*)d_in[4];
    const float* w_prev = (const float*)d_in[5];
    const float* mem    = (const float*)d_in[6];
    float* out          = (float*)d_out;

    const int B = in_sizes[0];            // beta is (B,1)
    const int N = in_sizes[5] / B;        // w_prev is (B,N)
    const int S = in_sizes[4] / B;        // s is (B,S)

    ntm_fused_kernel<<<B, NTHREADS, 0, stream>>>(
        beta, kappa, gamma, g, s, w_prev, mem, out, N, S);
}

// Round 6
// 53.999 us; speedup vs baseline: 1.1522x; 1.0043x over previous
//
#include <hip/hip_runtime.h>
#include <math.h>

#define EPS_COS 1e-8f
#define EPS_ADD 1e-12f

typedef float f4 __attribute__((ext_vector_type(4)));

// One block per batch (grid = B = 256 = #CUs), 1024 threads = 16 waves.
// Streaming pass: each wave reads a contiguous 4 KiB slice per round
// (16 rows x 256 B). Lane mapping within a round-chunk u: f4 index =
// wave*256 + u*64 + lane -> row = wave*16 + u*4 + (lane>>4), col = lane&15.
// Row reduction via DPP row_shl adds (VALU pipe): row_shl:N -> lane i reads
// lane i+N (OOB -> 0), so the 16-lane sum accumulates into lane 0 -- which is
// exactly the consumer lane. (R5 bug: row_shr accumulates into lane 15.)
// 8-deep register prefetch (two named f4[4] buffers, static indexing).
// Scores |t| < 1 (beta in [0,1), cos in [-1,1]) => exp needs no max subtract;
// softmax denominator accumulated inline. Assumes N == 4096, M == 64.

constexpr int NTHREADS = 1024;
constexpr int NWAVES   = NTHREADS / 64;   // 16
constexpr int MAX_N    = 4096;

// Sum over each 16-lane row; result valid in lane 0 of each 16-lane group.
__device__ __forceinline__ float row_sum16_lane0(float x) {
    int t;
    t = __builtin_amdgcn_update_dpp(0, __float_as_int(x), 0x108, 0xf, 0xf, true); // row_shl:8
    x += __int_as_float(t);
    t = __builtin_amdgcn_update_dpp(0, __float_as_int(x), 0x104, 0xf, 0xf, true); // row_shl:4
    x += __int_as_float(t);
    t = __builtin_amdgcn_update_dpp(0, __float_as_int(x), 0x102, 0xf, 0xf, true); // row_shl:2
    x += __int_as_float(t);
    t = __builtin_amdgcn_update_dpp(0, __float_as_int(x), 0x101, 0xf, 0xf, true); // row_shl:1
    x += __int_as_float(t);
    return x;
}

__global__ __launch_bounds__(NTHREADS, 1) void ntm_fused_kernel(
    const float* __restrict__ beta,    // [B,1]
    const float* __restrict__ kappa,   // [B,64]
    const float* __restrict__ gamma,   // [B,1]
    const float* __restrict__ g,       // [B,1]
    const float* __restrict__ s,       // [B,S]
    const float* __restrict__ w_prev,  // [B,N]
    const float* __restrict__ mem,     // [B,N,64]
    float* __restrict__ out,           // [B,N]
    int N, int S)
{
    const int b    = blockIdx.x;
    const int tid  = threadIdx.x;
    const int lane = tid & 63;
    const int wave = tid >> 6;
    const int l16  = lane & 15;
    const int rg   = lane >> 4;          // row within a 4-row chunk

    __shared__ float sh[MAX_N];          // e values -> interpolated weights
    __shared__ float red[NWAVES];

    // ---- prefetch w_prev into registers (overlaps the whole stream) ----
    const f4 wp_reg = reinterpret_cast<const f4*>(w_prev + (size_t)b * N)[tid];

    // ---- kappa fragment + norm ----
    f4 kv = reinterpret_cast<const f4*>(kappa + (size_t)b * 64)[l16];
    kv += (f4)EPS_ADD;
    float nb2 = kv.x * kv.x + kv.y * kv.y + kv.z * kv.z + kv.w * kv.w;
    nb2 = row_sum16_lane0(nb2);
    nb2 = __shfl(nb2, (lane >> 4) << 4);     // broadcast lane-0 sum to the group
    const float bscale = beta[b] / fmaxf(sqrtf(nb2), EPS_COS);

    // ---- streaming pass: 256 rows/round (16 waves x 16 rows) ----
    const int nIter = N >> 8;            // 16 for N=4096 (assume even, >=2)
    const int rowb  = wave * 16 + rg;    // + u*4 + it*256
    // per-wave base pointer: f4 index = wave*256 + lane
    const f4* p = reinterpret_cast<const f4*>(mem + (size_t)b * N * 64)
                  + (size_t)wave * 256 + lane;
    // iteration stride = 4096 f4 (256 rows); chunk stride = 64 f4 (1 KiB)

    float lsum = 0.0f;
    f4 aA[4], aB[4];
#pragma unroll
    for (int u = 0; u < 4; ++u) aA[u] = p[u * 64];
#pragma unroll
    for (int u = 0; u < 4; ++u) aB[u] = p[4096 + u * 64];

    for (int it = 0; it < nIter; it += 2) {
        // ---------- body A: compute round `it` from aA, refill aA for it+2 ----------
        {
            f4 c[4];
#pragma unroll
            for (int u = 0; u < 4; ++u) c[u] = aA[u];
            if (it + 2 < nIter) {
                const f4* pn = p + (size_t)(it + 2) * 4096;
#pragma unroll
                for (int u = 0; u < 4; ++u) aA[u] = pn[u * 64];
            }
#pragma unroll
            for (int u = 0; u < 4; ++u) {
                const f4 v = c[u];
                float d  = v.x * kv.x + v.y * kv.y + v.z * kv.z + v.w * kv.w;
                float n2 = v.x * v.x + v.y * v.y + v.z * v.z + v.w * v.w;
                d  = row_sum16_lane0(d);
                n2 = row_sum16_lane0(n2);
                if (l16 == 0) {
                    const float t = bscale * d * rsqrtf(fmaxf(n2, 1e-16f));
                    const float e = expf(t);
                    sh[rowb + u * 4 + it * 256] = e;
                    lsum += e;
                }
            }
        }
        // ---------- body B: compute round `it+1` from aB, refill aB for it+3 ----------
        {
            f4 c[4];
#pragma unroll
            for (int u = 0; u < 4; ++u) c[u] = aB[u];
            if (it + 3 < nIter) {
                const f4* pn = p + (size_t)(it + 3) * 4096;
#pragma unroll
                for (int u = 0; u < 4; ++u) aB[u] = pn[u * 64];
            }
#pragma unroll
            for (int u = 0; u < 4; ++u) {
                const f4 v = c[u];
                float d  = v.x * kv.x + v.y * kv.y + v.z * kv.z + v.w * kv.w;
                float n2 = v.x * v.x + v.y * v.y + v.z * v.z + v.w * v.w;
                d  = row_sum16_lane0(d);
                n2 = row_sum16_lane0(n2);
                if (l16 == 0) {
                    const float t = bscale * d * rsqrtf(fmaxf(n2, 1e-16f));
                    const float e = expf(t);
                    sh[rowb + u * 4 + (it + 1) * 256] = e;
                    lsum += e;
                }
            }
        }
    }

    // ---- block reduce: softmax denominator ----
#pragma unroll
    for (int m = 1; m < 64; m <<= 1) lsum += __shfl_xor(lsum, m);
    if (lane == 0) red[wave] = lsum;
    __syncthreads();                      // also covers all sh[] writes
    float tot = 0.0f;
#pragma unroll
    for (int i = 0; i < NWAVES; ++i) tot += red[i];

    // ---- interpolate in place (one f4 per thread) ----
    const float gv = g[b];
    const float ws = gv / tot;            // g * (e / tot)
    f4* sh4 = reinterpret_cast<f4*>(sh);
    {
        const f4 ev = sh4[tid];
        sh4[tid] = ws * ev + (1.0f - gv) * wp_reg;
    }
    __syncthreads();

    // ---- circular shift + sharpen (results stay in registers) ----
    const float gam = gamma[b];
    float sv[8];
    const int Sc = (S < 8) ? S : 8;
    for (int j = 0; j < Sc; ++j) sv[j] = s[(size_t)b * S + j];

    const int i0 = tid * 4;
    const int mask = N - 1;               // N is a power of two
    float o[4];
    float ssum = 0.0f;
#pragma unroll
    for (int k = 0; k < 4; ++k) {
        float wh = 0.0f;
        for (int j = 0; j < Sc; ++j) {
            const int idx = (i0 + k + j - 1) & mask;
            wh += sv[j] * sh[idx];
        }
        o[k] = powf(wh, gam);
        ssum += o[k];
    }

    // ---- block reduce: sharpen denominator ----
#pragma unroll
    for (int m = 1; m < 64; m <<= 1) ssum += __shfl_xor(ssum, m);
    if (lane == 0) red[wave] = ssum;      // safe: red reads (tot) were pre-barrier
    __syncthreads();
    float stot = 0.0f;
#pragma unroll
    for (int i = 0; i < NWAVES; ++i) stot += red[i];

    // ---- normalize + vector store ----
    const float inv_den = 1.0f / (stot + EPS_ADD);
    f4 ov;
    ov.x = o[0] * inv_den; ov.y = o[1] * inv_den;
    ov.z = o[2] * inv_den; ov.w = o[3] * inv_den;
    reinterpret_cast<f4*>(out + (size_t)b * N)[tid] = ov;
}

extern "C" void kernel_launch(void* const* d_in, const int* in_sizes, int n_in,
                              void* d_out, int out_size, void* d_ws, size_t ws_size,
                              hipStream_t stream) {
    const float* beta   = (const float*)d_in[0];
    const float* kappa  = (const float*)d_in[1];
    const float* gamma  = (const float*)d_in[2];
    const float* g      = (const float*)d_in[3];
    const float* s      = (const float*)d_in[4];
    const float* w_prev = (const float*)d_in[5];
    const float* mem    = (const float*)d_in[6];
    float* out          = (float*)d_out;

    const int B = in_sizes[0];            // beta is (B,1)
    const int N = in_sizes[5] / B;        // w_prev is (B,N)
    const int S = in_sizes[4] / B;        // s is (B,S)

    ntm_fused_kernel<<<B, NTHREADS, 0, stream>>>(
        beta, kappa, gamma, g, s, w_prev, mem, out, N, S);
}